// Round 1
// baseline (81.510 us; speedup 1.0000x reference)
//
#include <hip/hip_runtime.h>

// Brush-centric scatter rewrite.
// out[b,c,h,w] = (1/64) Σ_n Σ_p wy[h,p] Σ_q wx[w,q] patch[b,n,c,p,q]
// sigma=0.2 → support radius 2.5 px. For brush center g, the nonzero output
// window is w ∈ [g-10, g+11] → 22 integer columns with x0 = floor(g)-10
// (proof: ceil(a-2.5)+4 == floor(a+2.5) for all a, so 5 taps exactly cover
// the ±2.5 support; clamping qlo to [0,11] keeps taps in [0,16) while still
// covering the clipped support).
//
// Kernel 1: zero the 25.2 MB output (compulsory write, ~4.5 us).
// Kernel 2: one block per (b,n) — 2048 blocks = 8/CU, one dispatch round.
//   Phase A (no barrier): patch → LDS (3 coalesced loads/thread); threads
//     0..219 each compute ONE weight-table tap wT[axis][i][j] =
//     exp(-12.5 d²)/(Z(q)+eps) — each tap thread redundantly computes its
//     own 4-tap Z (5 exps total/thread, fully parallel, no cross-thread dep).
//     1/64 mean is folded into the x-axis table.
//   B1. Stage1: T[c][p][i] = Σ_j wx[i][j]·P[c][p][qlo(i)+j]  (352 items).
//   B2. Stage2: pixel (yi,xi): Σ_j wy[yi][j]·T[c][plo+j][xi], bounds-clip
//     to the canvas, 3 atomicAdd (different b never collide; same-b overlap
//     ~0.4 brushes/pixel → negligible contention; fp reorder error ~1e-7).
// Z truncation at the padded-canvas edge (coords in [-8,263]) matches the
// reference's F.sum over the padded grid, same 4-tap window as the previous
// passing kernel.

__global__ __launch_bounds__(256) void zero_out(float4* __restrict__ out)
{
    out[blockIdx.x * 256 + threadIdx.x] = make_float4(0.f, 0.f, 0.f, 0.f);
}

__global__ __launch_bounds__(256) void brush_scatter(
        const float* __restrict__ brushes,   // [32,64,2]
        const float* __restrict__ patches,   // [32,64,3,16,16]
        float* __restrict__ out)             // [32,3,256,256]
{
    const int n   = blockIdx.x;          // 64
    const int b   = blockIdx.y;          // 32
    const int tid = threadIdx.x;

    __shared__ float P[3 * 256];         // patch [c][p*16+q]
    __shared__ float wT[2][22][5];       // [axis][window i][tap j]
    __shared__ int   qloT[2][22];
    __shared__ float T[3 * 352];         // stage1 out [c][p*22+i]

    const int bn = (b << 6) + n;
    // uniform (scalar) brush coords
    const float gx = brushes[2 * bn]     * 256.0f;
    const float gy = brushes[2 * bn + 1] * 256.0f;
    const int x0 = (int)floorf(gx) - 10;
    const int y0 = (int)floorf(gy) - 10;

    // patch → LDS, coalesced, conflict-free (stride-256 word writes)
    const float* pb = patches + (size_t)bn * 768;
    P[tid]       = pb[tid];
    P[tid + 256] = pb[tid + 256];
    P[tid + 512] = pb[tid + 512];

    // weight tables: one tap per thread, no cross-thread dependencies
    if (tid < 220) {
        const int axis = tid / 110;          // 0=x, 1=y
        const int r    = tid - axis * 110;
        const int i    = r / 5;              // window position
        const int j    = r - i * 5;          // tap
        const float g    = axis ? gy : gx;
        const float wpos = (float)((axis ? y0 : x0) + i);
        const float a    = wpos - g + 7.5f;  // position in q-space
        int qlo = (int)ceilf(a - 2.5f);
        qlo = qlo < 0 ? 0 : (qlo > 11 ? 11 : qlo);
        const int q = qlo + j;
        const float mu = g + (float)q - 7.5f;
        // normalizer Z(q): sum over padded canvas coords within support
        const float fl = floorf(mu);
        float Z = 0.0f;
#pragma unroll
        for (int d = -1; d <= 2; ++d) {
            const float c = fl + (float)d;
            if (c >= -8.0f && c <= 263.0f) {     // padded coord range
                const float u = c - mu;
                Z += __expf(-12.5f * u * u);
            }
        }
        const float dd  = wpos - mu;             // |dd| <= 2.5 where it matters
        float wgt = __expf(-12.5f * dd * dd) / (Z + 1e-7f);
        if (axis == 0) wgt *= 0.015625f;         // fold 1/64 mean into x side
        wT[axis][i][j] = wgt;
        if (j == 0) qloT[axis][i] = qlo;
    }
    __syncthreads();                             // B1

    // stage1: T[c][p][i] = Σ_j wx[i][j] * P[c][p][qlo+j]
    for (int it = tid; it < 352; it += 256) {
        const int p = it / 22;
        const int i = it - p * 22;
        const int qlo = qloT[0][i];
        const float w0 = wT[0][i][0], w1 = wT[0][i][1], w2 = wT[0][i][2],
                    w3 = wT[0][i][3], w4 = wT[0][i][4];
        const float* Pp = &P[p * 16 + qlo];
#pragma unroll
        for (int c = 0; c < 3; ++c) {
            const float* Pc = Pp + c * 256;
            T[c * 352 + p * 22 + i] =
                w0 * Pc[0] + w1 * Pc[1] + w2 * Pc[2] + w3 * Pc[3] + w4 * Pc[4];
        }
    }
    __syncthreads();                             // B2

    // stage2: per-pixel y-contraction + atomic scatter
    float* ob = out + ((size_t)(b * 3) << 16);
    for (int e = tid; e < 484; e += 256) {
        const int yi = e / 22;
        const int xi = e - yi * 22;
        const int h = y0 + yi;
        const int w = x0 + xi;
        if (((unsigned)h < 256u) & ((unsigned)w < 256u)) {
            const int plo = qloT[1][yi];
            const float w0 = wT[1][yi][0], w1 = wT[1][yi][1], w2 = wT[1][yi][2],
                        w3 = wT[1][yi][3], w4 = wT[1][yi][4];
            float v0, v1, v2;
            {
                const float* Tc = &T[0 * 352 + plo * 22 + xi];
                v0 = w0*Tc[0] + w1*Tc[22] + w2*Tc[44] + w3*Tc[66] + w4*Tc[88];
            }
            {
                const float* Tc = &T[1 * 352 + plo * 22 + xi];
                v1 = w0*Tc[0] + w1*Tc[22] + w2*Tc[44] + w3*Tc[66] + w4*Tc[88];
            }
            {
                const float* Tc = &T[2 * 352 + plo * 22 + xi];
                v2 = w0*Tc[0] + w1*Tc[22] + w2*Tc[44] + w3*Tc[66] + w4*Tc[88];
            }
            // skip exact-underflow window edges (error bound 1e-12)
            if (fabsf(v0) + fabsf(v1) + fabsf(v2) > 1e-12f) {
                const int off = (h << 8) + w;
                atomicAdd(ob + off,               v0);
                atomicAdd(ob + off + (1 << 16),   v1);
                atomicAdd(ob + off + (2 << 16),   v2);
            }
        }
    }
}

extern "C" void kernel_launch(void* const* d_in, const int* in_sizes, int n_in,
                              void* d_out, int out_size, void* d_ws, size_t ws_size,
                              hipStream_t stream) {
    const float* brushes = (const float*)d_in[0];
    const float* patches = (const float*)d_in[1];
    float* out = (float*)d_out;
    // 32*3*256*256 floats = 1,572,864 float4 → 6144 blocks × 256
    zero_out<<<dim3(6144), dim3(256), 0, stream>>>((float4*)out);
    brush_scatter<<<dim3(64, 32), dim3(256), 0, stream>>>(brushes, patches, out);
}

// Round 2
// 80.046 us; speedup vs baseline: 1.0183x; 1.0183x over previous
//
#include <hip/hip_runtime.h>

// Brush-footprint precompute + tile gather (no atomics, no per-brush barriers).
//
// out[b,c,h,w] = (1/64) Σ_n Σ_p wy[h,p] Σ_q wx[w,q] patch[b,n,c,p,q]
// sigma=0.2 → support radius 2.5 px → each brush's nonzero output window is
// 22x22 px starting at (x0,y0) = (floor(gx)-10, floor(gy)-10).
//
// Kernel 1 (brush_prep, one block per (b,n)): computes the brush's full
//   22x22x3 separable footprint F into d_ws (2048 brushes × 1452 floats =
//   11.9 MB; d_ws is the 256 MiB poison-filled workspace). Same validated
//   weight math as the previous passing kernels (Z truncated to padded
//   canvas coords [-8,263], qlo clamped to [0,11], 1/64 folded into wx).
//   All 484 footprint entries are written unconditionally (ws is poisoned).
// Kernel 2 (tile_gather, one block per 16x16 tile): wave-0 ballot compacts
//   the ~1.3 brushes whose footprint overlaps the tile; each pixel then
//   just sums 3 F values per overlapping brush (plain loads, L2-resident)
//   and stores the final result. No atomics → no cross-XCD coherence-point
//   serialization (the previous scatter's ~34 us cost).

__global__ __launch_bounds__(256) void brush_prep(
        const float* __restrict__ brushes,   // [32,64,2]
        const float* __restrict__ patches,   // [32,64,3,16,16]
        float* __restrict__ F)               // [2048][3][484]
{
    const int n   = blockIdx.x;          // 64
    const int b   = blockIdx.y;          // 32
    const int tid = threadIdx.x;

    __shared__ float P[3 * 256];         // patch [c][p*16+q]
    __shared__ float wT[2][22][5];       // [axis][window i][tap j]
    __shared__ int   qloT[2][22];
    __shared__ float T[3 * 352];         // stage1 out [c][p*22+i]

    const int bn = (b << 6) + n;
    const float gx = brushes[2 * bn]     * 256.0f;
    const float gy = brushes[2 * bn + 1] * 256.0f;
    const int x0 = (int)floorf(gx) - 10;
    const int y0 = (int)floorf(gy) - 10;

    // patch → LDS, coalesced
    const float* pb = patches + (size_t)bn * 768;
    P[tid]       = pb[tid];
    P[tid + 256] = pb[tid + 256];
    P[tid + 512] = pb[tid + 512];

    // weight tables: one tap per thread, no cross-thread dependencies
    if (tid < 220) {
        const int axis = tid / 110;          // 0=x, 1=y
        const int r    = tid - axis * 110;
        const int i    = r / 5;              // window position
        const int j    = r - i * 5;          // tap
        const float g    = axis ? gy : gx;
        const float wpos = (float)((axis ? y0 : x0) + i);
        const float a    = wpos - g + 7.5f;  // position in q-space
        int qlo = (int)ceilf(a - 2.5f);
        qlo = qlo < 0 ? 0 : (qlo > 11 ? 11 : qlo);
        const int q = qlo + j;
        const float mu = g + (float)q - 7.5f;
        // normalizer Z(q): sum over padded canvas coords within support
        const float fl = floorf(mu);
        float Z = 0.0f;
#pragma unroll
        for (int d = -1; d <= 2; ++d) {
            const float c = fl + (float)d;
            if (c >= -8.0f && c <= 263.0f) {     // padded coord range
                const float u = c - mu;
                Z += __expf(-12.5f * u * u);
            }
        }
        const float dd  = wpos - mu;   // out-of-support taps underflow to 0
        float wgt = __expf(-12.5f * dd * dd) / (Z + 1e-7f);
        if (axis == 0) wgt *= 0.015625f;         // fold 1/64 mean into x side
        wT[axis][i][j] = wgt;
        if (j == 0) qloT[axis][i] = qlo;
    }
    __syncthreads();                             // B1

    // stage1: T[c][p][i] = Σ_j wx[i][j] * P[c][p][qlo+j]
    for (int it = tid; it < 352; it += 256) {
        const int p = it / 22;
        const int i = it - p * 22;
        const int qlo = qloT[0][i];
        const float w0 = wT[0][i][0], w1 = wT[0][i][1], w2 = wT[0][i][2],
                    w3 = wT[0][i][3], w4 = wT[0][i][4];
        const float* Pp = &P[p * 16 + qlo];
#pragma unroll
        for (int c = 0; c < 3; ++c) {
            const float* Pc = Pp + c * 256;
            T[c * 352 + p * 22 + i] =
                w0 * Pc[0] + w1 * Pc[1] + w2 * Pc[2] + w3 * Pc[3] + w4 * Pc[4];
        }
    }
    __syncthreads();                             // B2

    // stage2: y-contraction, write the full footprint (no clipping here)
    float* Fb = F + (size_t)bn * 1452;
    for (int e = tid; e < 484; e += 256) {
        const int yi = e / 22;
        const int xi = e - yi * 22;
        const int plo = qloT[1][yi];
        const float w0 = wT[1][yi][0], w1 = wT[1][yi][1], w2 = wT[1][yi][2],
                    w3 = wT[1][yi][3], w4 = wT[1][yi][4];
        const float* T0 = &T[0 * 352 + plo * 22 + xi];
        const float* T1 = &T[1 * 352 + plo * 22 + xi];
        const float* T2 = &T[2 * 352 + plo * 22 + xi];
        Fb[e]       = w0*T0[0] + w1*T0[22] + w2*T0[44] + w3*T0[66] + w4*T0[88];
        Fb[e + 484] = w0*T1[0] + w1*T1[22] + w2*T1[44] + w3*T1[66] + w4*T1[88];
        Fb[e + 968] = w0*T2[0] + w1*T2[22] + w2*T2[44] + w3*T2[66] + w4*T2[88];
    }
}

__global__ __launch_bounds__(256) void tile_gather(
        const float* __restrict__ brushes,   // [32,64,2]
        const float* __restrict__ F,         // [2048][3][484]
        float* __restrict__ out)             // [32,3,256,256]
{
    const int b   = blockIdx.z;
    const int tx  = blockIdx.x * 16;
    const int ty  = blockIdx.y * 16;
    const int tid = threadIdx.x;
    const int qi  = tid & 15;
    const int pi  = tid >> 4;
    const int w   = tx + qi;
    const int h   = ty + pi;

    __shared__ int2 org[64];                 // per-brush (x0,y0)
    __shared__ unsigned long long smask;

    if (tid < 64) {                          // exactly wave 0 → uniform ballot
        float2 g = ((const float2*)brushes)[(b << 6) + tid];
        const int x0 = (int)floorf(g.x * 256.0f) - 10;
        const int y0 = (int)floorf(g.y * 256.0f) - 10;
        org[tid] = make_int2(x0, y0);
        const bool hit = (x0 <= tx + 15) & (x0 + 21 >= tx) &
                         (y0 <= ty + 15) & (y0 + 21 >= ty);
        const unsigned long long m = __ballot(hit);
        if (tid == 0) smask = m;
    }
    __syncthreads();

    unsigned long long mask = smask;
    float a0 = 0.0f, a1 = 0.0f, a2 = 0.0f;
    const size_t bbase = (size_t)(b << 6) * 1452;
    while (mask) {
        const int n = __builtin_ctzll(mask);
        mask &= mask - 1;
        const int2 o = org[n];               // LDS broadcast (uniform n)
        const int xi = w - o.x;
        const int yi = h - o.y;
        if (((unsigned)xi < 22u) & ((unsigned)yi < 22u)) {
            const float* f = F + bbase + (size_t)n * 1452 + yi * 22 + xi;
            a0 += f[0];
            a1 += f[484];
            a2 += f[968];
        }
    }

    float* ob = out + (((size_t)(b * 3)) << 16) + (h << 8) + w;
    ob[0]       = a0;
    ob[1 << 16] = a1;
    ob[2 << 16] = a2;
}

extern "C" void kernel_launch(void* const* d_in, const int* in_sizes, int n_in,
                              void* d_out, int out_size, void* d_ws, size_t ws_size,
                              hipStream_t stream) {
    const float* brushes = (const float*)d_in[0];
    const float* patches = (const float*)d_in[1];
    float* out = (float*)d_out;
    float* F   = (float*)d_ws;   // 2048*1452*4 B = 11.9 MB (ws is 256 MiB)
    brush_prep<<<dim3(64, 32), dim3(256), 0, stream>>>(brushes, patches, F);
    tile_gather<<<dim3(16, 16, 32), dim3(256), 0, stream>>>(brushes, F, out);
}

// Round 3
// 79.678 us; speedup vs baseline: 1.0230x; 1.0046x over previous
//
#include <hip/hip_runtime.h>

// Fused single-launch tile gather (round-0 structure) with the per-brush
// barrier count halved: invZ for all ballot-surviving brushes is computed
// ONCE before the loop (8 survivors per 256-thread pass), and T4 is
// double-buffered so the loop needs only one __syncthreads per brush
// (stage1-write[buf] / B2 / stage2-read[buf], buf flips each iteration;
// the WAR between iter i's stage2 reads and iter i+2's stage1 writes is
// separated by iter i+1's barrier).
//
// out[b,c,h,w] = (1/64) Σ_n Σ_p wy[h,p] Σ_q wx[w,q] patch[b,n,c,p,q]
// sigma=0.2 → support 2.5 px; brush window <= 22x22 px. One block per
// 16x16 tile; wave-0 ballot compacts the brush list (~1.3 survivors/tile).
// stage1: thread (wi=tid&15, p=tid>>4) forms
//   T4[wi][p] = invZy[p] * Σ_j wx_j * (patch[:,p,qlo+j]*invZx[.])
//   via intra-wave __shfl (patch row p lives in the same wave). Shuffles
//   are executed by ALL lanes (uniform control flow); out-of-range lanes
//   mask via weights, not exec.
// Incremental Gaussian: w_{j+1}=w_j*u, u*=exp(-25); d0 clamped to [-3,3] so
// the chain stays finite for masked lanes (0*finite==0, no NaN).
// LDS ~19.5 KB → 8 blocks/CU (32 waves/CU = HW cap, no occupancy loss).

#define TILE 16

__global__ __launch_bounds__(256) void brush_tile(
        const float* __restrict__ brushes,   // [32,64,2]
        const float* __restrict__ patches,   // [32,64,3,16,16]
        float* __restrict__ out)             // [32,3,256,256]
{
    const int b   = blockIdx.z;
    const int tx  = blockIdx.x * TILE;
    const int ty  = blockIdx.y * TILE;
    const int tid = threadIdx.x;
    const int qi  = tid & 15;    // q (source) / wi (stage1) / w-col (stage2)
    const int pi  = tid >> 4;    // p (source, stage1) / h-row (stage2)
    const int w   = tx + qi;
    const int h   = ty + pi;

    __shared__ float  gxy[128];              // [n][{gx,gy}] px
    __shared__ unsigned long long smask;
    __shared__ unsigned char slist[64];      // survivor slot -> brush n
    __shared__ float  invZ[64][32];          // per survivor: [0..15]=x, [16..31]=y
    __shared__ float4 T4[2][16 * 21];        // double-buffered [wi][p(16)+pad5]

    // zero T4 pads of both buffers once (stage1 never writes p>=16)
    if (tid < 160) {
        const int bufi = tid / 80, r = tid - bufi * 80;
        T4[bufi][(r / 5) * 21 + 16 + (r % 5)] = make_float4(0, 0, 0, 0);
    }

    // wave 0: load + scale coords, ballot vs tile window, compact list
    if (tid < 64) {
        float2 g = ((const float2*)brushes)[(b << 6) + tid];
        g.x *= 256.0f; g.y *= 256.0f;
        ((float2*)gxy)[tid] = g;
        const bool hit =
            (g.x >= (float)tx - 9.5f) & (g.x <= (float)tx + 24.5f) &
            (g.y >= (float)ty - 9.5f) & (g.y <= (float)ty + 24.5f);
        const unsigned long long m = __ballot(hit);
        if (hit)
            slist[__popcll(m & ((1ull << tid) - 1ull))] = (unsigned char)tid;
        if (tid == 0) smask = m;
    }
    __syncthreads();                                     // B0
    const unsigned long long fullmask = smask;
    const int cnt = __popcll(fullmask);

    // precompute invZ for ALL survivors: 8 per pass (32 threads each),
    // disjoint writes, no cross-pass dependencies
    for (int k = tid >> 5; k < cnt; k += 8) {
        const int n    = slist[k];
        const int axis = (tid >> 4) & 1, q = tid & 15;
        const float g  = axis ? gxy[2 * n + 1] : gxy[2 * n];
        const float mu = g + (float)q - 7.5f;
        const float fl = floorf(mu);
        float Z = 0.0f;
#pragma unroll
        for (int d = -1; d <= 2; ++d) {
            const float c = fl + (float)d;
            if (c >= -8.0f && c <= 263.0f) {   // padded coord range
                const float u = c - mu;
                Z += __expf(-12.5f * u * u);
            }
        }
        invZ[k][tid & 31] = 1.0f / (Z + 1e-7f);
    }
    __syncthreads();                                     // B1 (once, pre-loop)

    float acc0 = 0.0f, acc1 = 0.0f, acc2 = 0.0f;
    const float E25 = 1.3887944e-11f;                    // exp(-25)
    unsigned long long mask = fullmask;
    int k = 0, buf = 0;

    while (mask) {
        const int n = __builtin_ctzll(mask);             // increasing n == slot k
        mask &= mask - 1;
        const float gx = gxy[2 * n], gy = gxy[2 * n + 1];

        // patch loads: 3 coalesced b32, latency overlaps the exp chains below
        const float* pb = patches + (size_t)((b << 6) + n) * 768;
        const float r0 = pb[tid];
        const float r1 = pb[tid + 256];
        const float r2 = pb[tid + 512];

        // pre-scale own patch element by invZx[its q]
        const float zx = invZ[k][qi];
        const float v0 = r0 * zx, v1 = r1 * zx, v2 = r2 * zx;

        // stage1: T4[buf][wi=qi][p=pi] via intra-wave shuffles — BRANCHLESS
        {
            const float ax  = (float)w - gx + 7.5f;
            const bool  okx = (ax >= -2.5f) & (ax <= 17.5f);
            int qlo = (int)ceilf(ax - 2.0f);
            qlo = qlo < 0 ? 0 : (qlo > 15 ? 15 : qlo);
            float d0 = ax - (float)qlo;
            d0 = fminf(fmaxf(d0, -3.0f), 3.0f);          // keep exp chain finite
            float wgt = okx ? __expf(-12.5f * d0 * d0) : 0.0f;
            float u   = __expf(25.0f * d0 - 12.5f);      // <= e^62.5, finite
            const int base = ((pi & 3) << 4) + qlo;      // intra-wave src lane
            float4 s = make_float4(0, 0, 0, 0);
#pragma unroll
            for (int j = 0; j < 5; ++j) {
                const float a0 = __shfl(v0, base + j, 64);  // all lanes active
                const float a1 = __shfl(v1, base + j, 64);
                const float a2 = __shfl(v2, base + j, 64);
                const float wj = (qlo + j < 16) ? wgt : 0.0f;
                s.x += wj * a0; s.y += wj * a1; s.z += wj * a2;
                wgt *= u; u *= E25;
            }
            const float zy = invZ[k][16 + pi];
            s.x *= zy; s.y *= zy; s.z *= zy;
            T4[buf][qi * 21 + pi] = s;
        }
        __syncthreads();                                 // B2 (only loop barrier)

        // stage2: 5 p-taps from T4[buf] row (pads are exact zeros; LDS reads
        // don't depend on other lanes' exec mask, so divergence is fine)
        {
            const float ay = (float)h - gy + 7.5f;
            if (ay >= -2.5f && ay <= 17.5f) {
                int plo = (int)ceilf(ay - 2.0f);
                plo = plo < 0 ? 0 : (plo > 15 ? 15 : plo);
                const float d0 = ay - (float)plo;        // in [-2.5, 2.5]
                float wgt = __expf(-12.5f * d0 * d0);
                float u   = __expf(25.0f * d0 - 12.5f);
                const float4* row = &T4[buf][qi * 21 + plo];
#pragma unroll
                for (int j = 0; j < 5; ++j) {
                    const float4 v = row[j];
                    acc0 += wgt * v.x; acc1 += wgt * v.y; acc2 += wgt * v.z;
                    wgt *= u; u *= E25;
                }
            }
        }
        ++k; buf ^= 1;
        // iter i+1 writes the OTHER buffer; iter i+2's write of this buffer
        // is separated from these reads by iter i+1's barrier
    }

    const float sc = 1.0f / 64.0f;
    float* ob = out + (((size_t)(b * 3)) << 16) + (h << 8) + w;
    ob[0]       = acc0 * sc;
    ob[1 << 16] = acc1 * sc;
    ob[2 << 16] = acc2 * sc;
}

extern "C" void kernel_launch(void* const* d_in, const int* in_sizes, int n_in,
                              void* d_out, int out_size, void* d_ws, size_t ws_size,
                              hipStream_t stream) {
    const float* brushes = (const float*)d_in[0];
    const float* patches = (const float*)d_in[1];
    float* out = (float*)d_out;
    brush_tile<<<dim3(16, 16, 32), dim3(256), 0, stream>>>(brushes, patches, out);
}